// Round 8
// baseline (40873.834 us; speedup 1.0000x reference)
//
#include <hip/hip_runtime.h>
#include <hip/hip_bf16.h>

#define B_   8
#define N_   1024
#define C_   768
#define H_   12
#define HD_  64
#define BH_  96
#define SCALE_ 0.125f
#define NIT_ 5

// ---------------------------------------------------------------------------
// K1 naive: qkv[m][c2] = x[m]·W[:,c2] + b[c2], scattered into k/v [B,H,N,HD].
// One thread per output element. grid 49152 x 256.
// ---------------------------------------------------------------------------
__global__ __launch_bounds__(256)
void qkv_naive(const float* __restrict__ X, const float* __restrict__ W,
               const float* __restrict__ bias,
               float* __restrict__ Kb, float* __restrict__ Vb)
{
    const int idx = blockIdx.x * 256 + threadIdx.x;     // [0, 8192*1536)
    const int m  = idx / 1536;
    const int c2 = idx - m * 1536;

    const float* xp = X + (size_t)m * C_;
    const float* wp = W + c2;
    float acc = 0.0f;
    for (int k = 0; k < C_; ++k) acc += xp[k] * wp[(size_t)k * 1536];
    acc += bias[c2];

    const int which = (c2 >= C_) ? 1 : 0;
    const int cc = c2 - which * C_;
    const int h = cc >> 6, d = cc & 63;
    const int b = m >> 10, n = m & 1023;
    float* tgt = which ? Vb : Kb;
    tgt[(((size_t)(b * H_ + h) * N_) + n) * HD_ + d] = acc;
}

// ---------------------------------------------------------------------------
// K2: mu[bh] = (N*C/4) / sum|k| per (b,h). grid 96 x 256.
// ---------------------------------------------------------------------------
__global__ __launch_bounds__(256)
void musum(const float* __restrict__ Kb, float* __restrict__ mu)
{
    const int bh = blockIdx.x;
    const int tid = threadIdx.x;
    const float* p = Kb + (size_t)bh * (N_ * HD_);
    float s = 0.0f;
    for (int i = tid; i < N_ * HD_; i += 256) s += fabsf(p[i]);
    for (int off = 32; off; off >>= 1) s += __shfl_down(s, off, 64);
    __shared__ float red[4];
    if ((tid & 63) == 0) red[tid >> 6] = s;
    __syncthreads();
    if (tid == 0)
        mu[bh] = (float)(N_ * C_ / 4.0) / (red[0] + red[1] + red[2] + red[3]);
}

// ---------------------------------------------------------------------------
// K3: t = k - l + y/mu; s = soft_threshold(t, 4*mu); k2 = k - s - y/mu
// ---------------------------------------------------------------------------
__global__ __launch_bounds__(256)
void ew_sk2(const float* __restrict__ Kb, const float* __restrict__ Lb,
            const float* __restrict__ Yb, const float* __restrict__ mu,
            float* __restrict__ K2b)
{
    const int i = blockIdx.x * 256 + threadIdx.x;
    const int bh = i >> 16;
    const float m = mu[bh];
    const float lm = 4.0f * m;
    const float yom = Yb[i] / m;
    const float kv = Kb[i];
    const float t = kv - Lb[i] + yom;
    const float s = (t >= lm) ? (t - lm) : ((t <= -lm) ? (t + lm) : 0.0f);
    K2b[i] = kv - s - yom;
}

// ---------------------------------------------------------------------------
// K5: y_new = y + mu*(k - l - s) == 2*y + mu*(k2 - l)  (exact identity,
// since ew_sk2 defines k2 := k - s - y/mu; uses y_old, k2, l_new)
// ---------------------------------------------------------------------------
__global__ __launch_bounds__(256)
void ew_y(float* __restrict__ Yb, const float* __restrict__ K2b,
          const float* __restrict__ Lb, const float* __restrict__ mu)
{
    const int i = blockIdx.x * 256 + threadIdx.x;
    const int bh = i >> 16;
    const float m = mu[bh];
    Yb[i] = 2.0f * Yb[i] + m * (K2b[i] - Lb[i]);
}

// ---------------------------------------------------------------------------
// K4 naive attention, two-pass true-max softmax. One block per (q, bh).
// l = softmax(k2 k2^T / 8) @ v ; on write_attn, emits the fp32 attn row.
// ---------------------------------------------------------------------------
__global__ __launch_bounds__(256)
void attn_naive(const float* __restrict__ K2, const float* __restrict__ V,
                float* __restrict__ L, float* __restrict__ A,
                int write_attn)
{
    __shared__ float qs[64];
    __shared__ float Ss[1024];
    __shared__ float red[256];

    const int tid = threadIdx.x;
    const int q = blockIdx.x;
    const int bh = blockIdx.y;
    const float* k2b = K2 + (size_t)bh * (N_ * HD_);
    const float* vbh = V + (size_t)bh * (N_ * HD_);

    if (tid < 64) qs[tid] = k2b[(size_t)q * HD_ + tid];
    __syncthreads();

    float lmax = -1e30f;
    const float4* q4 = (const float4*)qs;
    for (int m = tid; m < N_; m += 256) {
        const float4* k4 = (const float4*)(k2b + (size_t)m * HD_);
        float s = 0.0f;
#pragma unroll
        for (int d4 = 0; d4 < 16; ++d4) {
            float4 a = q4[d4], b = k4[d4];
            s += a.x * b.x + a.y * b.y + a.z * b.z + a.w * b.w;
        }
        s *= SCALE_;
        Ss[m] = s;
        lmax = fmaxf(lmax, s);
    }
    red[tid] = lmax;
    __syncthreads();
    for (int st = 128; st; st >>= 1) {
        if (tid < st) red[tid] = fmaxf(red[tid], red[tid + st]);
        __syncthreads();
    }
    const float mrow = red[0];
    __syncthreads();

    float zp = 0.0f;
    for (int m = tid; m < N_; m += 256) {
        float p = __expf(Ss[m] - mrow);
        Ss[m] = p;
        zp += p;
    }
    red[tid] = zp;
    __syncthreads();
    for (int st = 128; st; st >>= 1) {
        if (tid < st) red[tid] += red[tid + st];
        __syncthreads();
    }
    const float zinv = 1.0f / red[0];
    __syncthreads();

    const int c = tid >> 6, d = tid & 63;
    float part = 0.0f;
    const int m0 = c * 256;
    for (int m = m0; m < m0 + 256; ++m)
        part += Ss[m] * vbh[(size_t)m * HD_ + d];
    red[tid] = part;
    __syncthreads();
    if (tid < 64) {
        float lv = (red[tid] + red[64 + tid] + red[128 + tid] + red[192 + tid]) * zinv;
        L[(size_t)bh * (N_ * HD_) + (size_t)q * HD_ + tid] = lv;
    }

    if (write_attn) {
        float* arow = A + ((size_t)(bh * N_ + q)) * N_;
        for (int m = tid; m < N_; m += 256)
            arow[m] = Ss[m] * zinv;
    }
}

// ---------------------------------------------------------------------------
// K7 naive proj: out[m][cc] = sum_k l_t[m][k] * Wp[k][cc] + bp[cc], fp32 out.
// l_t[m][k] = l[b, h=k>>6, n, d=k&63], m = b*N+n.  grid 24576 x 256.
// ---------------------------------------------------------------------------
__global__ __launch_bounds__(256)
void proj_naive(const float* __restrict__ Lb, const float* __restrict__ W,
                const float* __restrict__ bias, float* __restrict__ Out)
{
    const int idx = blockIdx.x * 256 + threadIdx.x;     // [0, 8192*768)
    const int m = idx / C_;
    const int cc = idx - m * C_;
    const int b = m >> 10, n = m & 1023;

    const float* lbase = Lb + (((size_t)b * H_) * N_ + n) * HD_;
    const float* wp = W + cc;
    float acc = 0.0f;
    for (int k = 0; k < C_; ++k) {
        const int h = k >> 6, d = k & 63;
        acc += lbase[(size_t)h * (N_ * HD_) + d] * wp[(size_t)k * C_];
    }
    acc += bias[cc];
    Out[(size_t)m * C_ + cc] = acc;
}

// ---------------------------------------------------------------------------
// d_out is FLOAT32: out = d_out[0 .. 6291456), attn = d_out[6291456 .. ).
// ws (floats): kb@0, vb@SZ, lb@2SZ, yb@3SZ, k2b@4SZ, mu@5SZ (128 pad).
// ---------------------------------------------------------------------------
extern "C" void kernel_launch(void* const* d_in, const int* in_sizes, int n_in,
                              void* d_out, int out_size, void* d_ws, size_t ws_size,
                              hipStream_t stream)
{
    (void)in_sizes; (void)n_in; (void)out_size; (void)ws_size;

    const float* x  = (const float*)d_in[0];
    const float* Wq = (const float*)d_in[1];
    const float* bq = (const float*)d_in[2];
    const float* Wp = (const float*)d_in[3];
    const float* bp = (const float*)d_in[4];

    float* out_f  = (float*)d_out;
    float* attn_f = out_f + (size_t)B_ * N_ * C_;

    const size_t SZ = (size_t)BH_ * N_ * HD_;   // 6,291,456 floats
    float* ws  = (float*)d_ws;
    float* kb  = ws;
    float* vb  = ws + SZ;
    float* lb  = ws + 2 * SZ;
    float* yb  = ws + 3 * SZ;
    float* k2b = ws + 4 * SZ;
    float* mu  = ws + 5 * SZ;                   // 96 floats (pad 128)

    hipMemsetAsync(lb, 0, SZ * sizeof(float), stream);
    hipMemsetAsync(yb, 0, SZ * sizeof(float), stream);

    qkv_naive<<<49152, 256, 0, stream>>>(x, Wq, bq, kb, vb);
    musum<<<96, 256, 0, stream>>>(kb, mu);

    for (int it = 0; it <= NIT_; ++it) {
        ew_sk2<<<24576, 256, 0, stream>>>(kb, lb, yb, mu, k2b);
        attn_naive<<<dim3(N_, BH_), 256, 0, stream>>>(
            k2b, vb, lb, attn_f, (it == NIT_) ? 1 : 0);
        if (it < NIT_)
            ew_y<<<24576, 256, 0, stream>>>(yb, k2b, lb, mu);
    }

    proj_naive<<<24576, 256, 0, stream>>>(lb, Wp, bp, out_f);
}

// Round 9
// 7274.753 us; speedup vs baseline: 5.6186x; 5.6186x over previous
//
#include <hip/hip_runtime.h>
#include <hip/hip_bf16.h>

#define B_   8
#define N_   1024
#define C_   768
#define H_   12
#define HD_  64
#define BH_  96
#define SCALE_ 0.125f
#define NIT_ 5

// ---------------------------------------------------------------------------
// K1 naive: qkv[m][c2] = x[m]·W[:,c2] + b[c2], scattered into k/v [B,H,N,HD].
// (verified R8)  grid 49152 x 256.
// ---------------------------------------------------------------------------
__global__ __launch_bounds__(256)
void qkv_naive(const float* __restrict__ X, const float* __restrict__ W,
               const float* __restrict__ bias,
               float* __restrict__ Kb, float* __restrict__ Vb)
{
    const int idx = blockIdx.x * 256 + threadIdx.x;     // [0, 8192*1536)
    const int m  = idx / 1536;
    const int c2 = idx - m * 1536;

    const float* xp = X + (size_t)m * C_;
    const float* wp = W + c2;
    float acc = 0.0f;
    for (int k = 0; k < C_; ++k) acc += xp[k] * wp[(size_t)k * 1536];
    acc += bias[c2];

    const int which = (c2 >= C_) ? 1 : 0;
    const int cc = c2 - which * C_;
    const int h = cc >> 6, d = cc & 63;
    const int b = m >> 10, n = m & 1023;
    float* tgt = which ? Vb : Kb;
    tgt[(((size_t)(b * H_ + h) * N_) + n) * HD_ + d] = acc;
}

// ---------------------------------------------------------------------------
// K2: mu[bh] = (N*C/4) / sum|k| per (b,h).  (verified R8)
// ---------------------------------------------------------------------------
__global__ __launch_bounds__(256)
void musum(const float* __restrict__ Kb, float* __restrict__ mu)
{
    const int bh = blockIdx.x;
    const int tid = threadIdx.x;
    const float* p = Kb + (size_t)bh * (N_ * HD_);
    float s = 0.0f;
    for (int i = tid; i < N_ * HD_; i += 256) s += fabsf(p[i]);
    for (int off = 32; off; off >>= 1) s += __shfl_down(s, off, 64);
    __shared__ float red[4];
    if ((tid & 63) == 0) red[tid >> 6] = s;
    __syncthreads();
    if (tid == 0)
        mu[bh] = (float)(N_ * C_ / 4.0) / (red[0] + red[1] + red[2] + red[3]);
}

// ---------------------------------------------------------------------------
// K3: t = k - l + y/mu; s = soft_threshold(t, 4*mu); k2 = k - s - y/mu
// (verified R8)
// ---------------------------------------------------------------------------
__global__ __launch_bounds__(256)
void ew_sk2(const float* __restrict__ Kb, const float* __restrict__ Lb,
            const float* __restrict__ Yb, const float* __restrict__ mu,
            float* __restrict__ K2b)
{
    const int i = blockIdx.x * 256 + threadIdx.x;
    const int bh = i >> 16;
    const float m = mu[bh];
    const float lm = 4.0f * m;
    const float yom = Yb[i] / m;
    const float kv = Kb[i];
    const float t = kv - Lb[i] + yom;
    const float s = (t >= lm) ? (t - lm) : ((t <= -lm) ? (t + lm) : 0.0f);
    K2b[i] = kv - s - yom;
}

// ---------------------------------------------------------------------------
// K5: y_new = 2*y + mu*(k2 - l)  (verified R8)
// ---------------------------------------------------------------------------
__global__ __launch_bounds__(256)
void ew_y(float* __restrict__ Yb, const float* __restrict__ K2b,
          const float* __restrict__ Lb, const float* __restrict__ mu)
{
    const int i = blockIdx.x * 256 + threadIdx.x;
    const int bh = i >> 16;
    const float m = mu[bh];
    Yb[i] = 2.0f * Yb[i] + m * (K2b[i] - Lb[i]);
}

// ---------------------------------------------------------------------------
// K4 flash: l = softmax(k2 k2^T * SCALE) @ v, online softmax, 64x64 tiles.
// Thread (tx,ty) owns rows 4ty+i, score-columns tx+16j (LDS-conflict-free),
// output columns 4tx+c.  Saves per-row max/denominator for attn recompute.
// grid (16, 96) x 256.
// ---------------------------------------------------------------------------
__global__ __launch_bounds__(256)
void flash(const float* __restrict__ K2v, const float* __restrict__ Vv,
           float* __restrict__ Lout, float* __restrict__ Mrow,
           float* __restrict__ Zrow)
{
    __shared__ float Qs[64][68];
    __shared__ float Ks[64][68];
    __shared__ float Vs[64][68];
    __shared__ float Ps[64][68];
    __shared__ float m_sm[64], z_sm[64];

    const int tid = threadIdx.x;
    const int tx = tid & 15, ty = tid >> 4;
    const int bh = blockIdx.y;
    const int q0 = blockIdx.x * 64;
    const float* k2b = K2v + (size_t)bh * N_ * HD_;
    const float* vb  = Vv  + (size_t)bh * N_ * HD_;

    {
        int e = tid;
#pragma unroll
        for (int t = 0; t < 4; ++t, e += 256) {
            int r = e >> 4, c4 = (e & 15) << 2;
            *(float4*)&Qs[r][c4] =
                *(const float4*)(k2b + (size_t)(q0 + r) * HD_ + c4);
        }
    }
    if (tid < 64) { m_sm[tid] = -1e30f; z_sm[tid] = 0.0f; }

    float O[4][4];
#pragma unroll
    for (int i = 0; i < 4; ++i)
#pragma unroll
        for (int j = 0; j < 4; ++j) O[i][j] = 0.0f;

    for (int kt = 0; kt < 16; ++kt) {
        __syncthreads();   // prev PV reads done; Q/m_sm init visible on kt==0
        {
            int e = tid;
#pragma unroll
            for (int t = 0; t < 4; ++t, e += 256) {
                int r = e >> 4, c4 = (e & 15) << 2;
                size_t g = (size_t)(kt * 64 + r) * HD_ + c4;
                *(float4*)&Ks[r][c4] = *(const float4*)(k2b + g);
                *(float4*)&Vs[r][c4] = *(const float4*)(vb + g);
            }
        }
        __syncthreads();

        // S[i][j] = (Q row 4ty+i) . (K row tx+16j), over d = 0..63
        float S[4][4] = {};
#pragma unroll 4
        for (int d4 = 0; d4 < 16; ++d4) {
            float4 a[4], b[4];
#pragma unroll
            for (int i = 0; i < 4; ++i) a[i] = *(const float4*)&Qs[4 * ty + i][4 * d4];
#pragma unroll
            for (int j = 0; j < 4; ++j) b[j] = *(const float4*)&Ks[tx + 16 * j][4 * d4];
#pragma unroll
            for (int i = 0; i < 4; ++i)
#pragma unroll
                for (int j = 0; j < 4; ++j)
                    S[i][j] += a[i].x * b[j].x + a[i].y * b[j].y +
                               a[i].z * b[j].z + a[i].w * b[j].w;
        }
#pragma unroll
        for (int i = 0; i < 4; ++i)
#pragma unroll
            for (int j = 0; j < 4; ++j) S[i][j] *= SCALE_;

        // per-row tile max across 16 tx lanes
        float mt[4];
#pragma unroll
        for (int i = 0; i < 4; ++i)
            mt[i] = fmaxf(fmaxf(S[i][0], S[i][1]), fmaxf(S[i][2], S[i][3]));
        for (int off = 8; off; off >>= 1)
#pragma unroll
            for (int i = 0; i < 4; ++i)
                mt[i] = fmaxf(mt[i], __shfl_xor(mt[i], off, 16));

        float mnew[4], alpha[4], zs[4];
#pragma unroll
        for (int i = 0; i < 4; ++i) {
            const int r = 4 * ty + i;
            const float mo = m_sm[r];
            mnew[i] = fmaxf(mo, mt[i]);
            alpha[i] = __expf(mo - mnew[i]);
            zs[i] = 0.0f;
#pragma unroll
            for (int j = 0; j < 4; ++j) {
                S[i][j] = __expf(S[i][j] - mnew[i]);
                zs[i] += S[i][j];
            }
        }
        for (int off = 8; off; off >>= 1)
#pragma unroll
            for (int i = 0; i < 4; ++i) zs[i] += __shfl_xor(zs[i], off, 16);

#pragma unroll
        for (int i = 0; i < 4; ++i)
#pragma unroll
            for (int j = 0; j < 4; ++j)
                Ps[4 * ty + i][tx + 16 * j] = S[i][j];

        if (tx == 0) {
#pragma unroll
            for (int i = 0; i < 4; ++i) {
                const int r = 4 * ty + i;
                z_sm[r] = z_sm[r] * alpha[i] + zs[i];
                m_sm[r] = mnew[i];
            }
        }
#pragma unroll
        for (int i = 0; i < 4; ++i)
#pragma unroll
            for (int j = 0; j < 4; ++j) O[i][j] *= alpha[i];

        __syncthreads();   // Ps fully written, Vs loaded

        // O[i][c] += sum_m Ps[4ty+i][m] * Vs[m][4tx+c]
#pragma unroll 4
        for (int j4 = 0; j4 < 16; ++j4) {
            float4 vr[4];
#pragma unroll
            for (int q = 0; q < 4; ++q)
                vr[q] = *(const float4*)&Vs[4 * j4 + q][4 * tx];
#pragma unroll
            for (int i = 0; i < 4; ++i) {
                float4 pr = *(const float4*)&Ps[4 * ty + i][4 * j4];
                O[i][0] += pr.x * vr[0].x + pr.y * vr[1].x + pr.z * vr[2].x + pr.w * vr[3].x;
                O[i][1] += pr.x * vr[0].y + pr.y * vr[1].y + pr.z * vr[2].y + pr.w * vr[3].y;
                O[i][2] += pr.x * vr[0].z + pr.y * vr[1].z + pr.z * vr[2].z + pr.w * vr[3].z;
                O[i][3] += pr.x * vr[0].w + pr.y * vr[1].w + pr.z * vr[2].w + pr.w * vr[3].w;
            }
        }
    }

#pragma unroll
    for (int i = 0; i < 4; ++i) {
        const int r = 4 * ty + i;
        const float zinv = 1.0f / z_sm[r];
        float4 o4 = make_float4(O[i][0] * zinv, O[i][1] * zinv,
                                O[i][2] * zinv, O[i][3] * zinv);
        *(float4*)(Lout + ((size_t)bh * N_ + q0 + r) * HD_ + 4 * tx) = o4;
    }
    if (tx == 0) {
#pragma unroll
        for (int i = 0; i < 4; ++i) {
            const int r = 4 * ty + i;
            Mrow[(size_t)bh * N_ + q0 + r] = m_sm[r];
            Zrow[(size_t)bh * N_ + q0 + r] = z_sm[r];
        }
    }
}

// ---------------------------------------------------------------------------
// K6: recompute final scores from k2 + saved (m, Z); write fp32 attn.
// grid (16, 96) x 256.
// ---------------------------------------------------------------------------
__global__ __launch_bounds__(256)
void attn_out(const float* __restrict__ K2v, const float* __restrict__ Mrow,
              const float* __restrict__ Zrow, float* __restrict__ A)
{
    __shared__ float Qs[64][68];
    __shared__ float Ks[64][68];
    const int tid = threadIdx.x;
    const int tx = tid & 15, ty = tid >> 4;
    const int bh = blockIdx.y;
    const int q0 = blockIdx.x * 64;
    const float* k2b = K2v + (size_t)bh * N_ * HD_;

    {
        int e = tid;
#pragma unroll
        for (int t = 0; t < 4; ++t, e += 256) {
            int r = e >> 4, c4 = (e & 15) << 2;
            *(float4*)&Qs[r][c4] =
                *(const float4*)(k2b + (size_t)(q0 + r) * HD_ + c4);
        }
    }
    float mi[4], zi[4];
#pragma unroll
    for (int i = 0; i < 4; ++i) {
        const int r = q0 + 4 * ty + i;
        mi[i] = Mrow[(size_t)bh * N_ + r];
        zi[i] = 1.0f / Zrow[(size_t)bh * N_ + r];
    }

    for (int kt = 0; kt < 16; ++kt) {
        __syncthreads();
        {
            int e = tid;
#pragma unroll
            for (int t = 0; t < 4; ++t, e += 256) {
                int r = e >> 4, c4 = (e & 15) << 2;
                *(float4*)&Ks[r][c4] =
                    *(const float4*)(k2b + (size_t)(kt * 64 + r) * HD_ + c4);
            }
        }
        __syncthreads();

        float S[4][4] = {};
#pragma unroll 4
        for (int d4 = 0; d4 < 16; ++d4) {
            float4 a[4], b[4];
#pragma unroll
            for (int i = 0; i < 4; ++i) a[i] = *(const float4*)&Qs[4 * ty + i][4 * d4];
#pragma unroll
            for (int j = 0; j < 4; ++j) b[j] = *(const float4*)&Ks[tx + 16 * j][4 * d4];
#pragma unroll
            for (int i = 0; i < 4; ++i)
#pragma unroll
                for (int j = 0; j < 4; ++j)
                    S[i][j] += a[i].x * b[j].x + a[i].y * b[j].y +
                               a[i].z * b[j].z + a[i].w * b[j].w;
        }
#pragma unroll
        for (int i = 0; i < 4; ++i) {
            float* arow = A + ((size_t)(bh * N_ + q0 + 4 * ty + i)) * N_ + kt * 64;
#pragma unroll
            for (int j = 0; j < 4; ++j)
                arow[tx + 16 * j] = __expf(S[i][j] * SCALE_ - mi[i]) * zi[i];
        }
    }
}

// ---------------------------------------------------------------------------
// K7 naive proj (verified R8). grid 24576 x 256.
// ---------------------------------------------------------------------------
__global__ __launch_bounds__(256)
void proj_naive(const float* __restrict__ Lb, const float* __restrict__ W,
                const float* __restrict__ bias, float* __restrict__ Out)
{
    const int idx = blockIdx.x * 256 + threadIdx.x;     // [0, 8192*768)
    const int m = idx / C_;
    const int cc = idx - m * C_;
    const int b = m >> 10, n = m & 1023;

    const float* lbase = Lb + (((size_t)b * H_) * N_ + n) * HD_;
    const float* wp = W + cc;
    float acc = 0.0f;
    for (int k = 0; k < C_; ++k) {
        const int h = k >> 6, d = k & 63;
        acc += lbase[(size_t)h * (N_ * HD_) + d] * wp[(size_t)k * C_];
    }
    acc += bias[cc];
    Out[(size_t)m * C_ + cc] = acc;
}

// ---------------------------------------------------------------------------
// d_out is FLOAT32: out = d_out[0 .. 6291456), attn = d_out[6291456 .. ).
// ws (floats): kb@0, vb@SZ, lb@2SZ, yb@3SZ, k2b@4SZ, mu@5SZ(128), rowm, rowz.
// ---------------------------------------------------------------------------
extern "C" void kernel_launch(void* const* d_in, const int* in_sizes, int n_in,
                              void* d_out, int out_size, void* d_ws, size_t ws_size,
                              hipStream_t stream)
{
    (void)in_sizes; (void)n_in; (void)out_size; (void)ws_size;

    const float* x  = (const float*)d_in[0];
    const float* Wq = (const float*)d_in[1];
    const float* bq = (const float*)d_in[2];
    const float* Wp = (const float*)d_in[3];
    const float* bp = (const float*)d_in[4];

    float* out_f  = (float*)d_out;
    float* attn_f = out_f + (size_t)B_ * N_ * C_;

    const size_t SZ = (size_t)BH_ * N_ * HD_;   // 6,291,456 floats
    float* ws   = (float*)d_ws;
    float* kb   = ws;
    float* vb   = ws + SZ;
    float* lb   = ws + 2 * SZ;
    float* yb   = ws + 3 * SZ;
    float* k2b  = ws + 4 * SZ;
    float* mu   = ws + 5 * SZ;                  // 96 floats (pad 128)
    float* rowm = mu + 128;                     // BH*N
    float* rowz = rowm + (size_t)BH_ * N_;      // BH*N

    hipMemsetAsync(lb, 0, SZ * sizeof(float), stream);
    hipMemsetAsync(yb, 0, SZ * sizeof(float), stream);

    qkv_naive<<<49152, 256, 0, stream>>>(x, Wq, bq, kb, vb);
    musum<<<96, 256, 0, stream>>>(kb, mu);

    for (int it = 0; it <= NIT_; ++it) {
        ew_sk2<<<24576, 256, 0, stream>>>(kb, lb, yb, mu, k2b);
        flash<<<dim3(16, 96), 256, 0, stream>>>(k2b, vb, lb, rowm, rowz);
        if (it < NIT_)
            ew_y<<<24576, 256, 0, stream>>>(yb, k2b, lb, mu);
    }

    attn_out<<<dim3(16, 96), 256, 0, stream>>>(k2b, rowm, rowz, attn_f);
    proj_naive<<<24576, 256, 0, stream>>>(lb, Wp, bp, out_f);
}

// Round 10
// 3845.687 us; speedup vs baseline: 10.6285x; 1.8917x over previous
//
#include <hip/hip_runtime.h>
#include <hip/hip_bf16.h>

#define B_   8
#define N_   1024
#define C_   768
#define H_   12
#define HD_  64
#define BH_  96
#define SCALE_ 0.125f
#define NIT_ 5

// ---------------------------------------------------------------------------
// K1 tiled: qkv = x @ W_qkv + b_qkv (fp32), scattered into k/v [B,H,N,HD].
// grid (1536/64=24, 8192/64=128), block 256 (16x16 logical, 4x4 per thread).
// ---------------------------------------------------------------------------
__global__ __launch_bounds__(256)
void qkv_gemm(const float* __restrict__ X, const float* __restrict__ W,
              const float* __restrict__ bias,
              float* __restrict__ Kb, float* __restrict__ Vb)
{
    __shared__ float As[64][17];
    __shared__ float Bs[16][68];
    const int tid = threadIdx.x;
    const int tx = tid & 15, ty = tid >> 4;
    const int m0 = blockIdx.y * 64;
    const int c0 = blockIdx.x * 64;      // [0, 1536)
    const int ar = tid >> 2, ak4 = (tid & 3) << 2;
    const int bk = tid >> 4, bc4 = (tid & 15) << 2;

    float acc[4][4] = {};

    for (int kt = 0; kt < 48; ++kt) {
        __syncthreads();
        float4 av = *(const float4*)(X + (size_t)(m0 + ar) * C_ + kt * 16 + ak4);
        As[ar][ak4 + 0] = av.x; As[ar][ak4 + 1] = av.y;
        As[ar][ak4 + 2] = av.z; As[ar][ak4 + 3] = av.w;
        *(float4*)&Bs[bk][bc4] =
            *(const float4*)(W + (size_t)(kt * 16 + bk) * (2 * C_) + c0 + bc4);
        __syncthreads();
#pragma unroll
        for (int kk = 0; kk < 16; ++kk) {
            float a_[4];
#pragma unroll
            for (int i = 0; i < 4; ++i) a_[i] = As[4 * ty + i][kk];
            float4 b_ = *(const float4*)&Bs[kk][4 * tx];
#pragma unroll
            for (int i = 0; i < 4; ++i) {
                acc[i][0] += a_[i] * b_.x;
                acc[i][1] += a_[i] * b_.y;
                acc[i][2] += a_[i] * b_.z;
                acc[i][3] += a_[i] * b_.w;
            }
        }
    }

    const int cbase = c0 + 4 * tx;               // within [c0, c0+64)
    const int h = (c0 % C_) >> 6;                // head is constant per block
    float* tgt = (c0 < C_) ? Kb : Vb;
    const float b0 = bias[cbase + 0], b1 = bias[cbase + 1];
    const float b2 = bias[cbase + 2], b3 = bias[cbase + 3];
#pragma unroll
    for (int i = 0; i < 4; ++i) {
        int m = m0 + 4 * ty + i;
        int b = m >> 10, n = m & 1023;
        float4 o;
        o.x = acc[i][0] + b0;
        o.y = acc[i][1] + b1;
        o.z = acc[i][2] + b2;
        o.w = acc[i][3] + b3;
        *(float4*)(tgt + ((size_t)(b * H_ + h) * N_ + n) * HD_ + 4 * tx) = o;
    }
}

// ---------------------------------------------------------------------------
// K2: mu[bh] = (N*C/4) / sum|k| per (b,h).  (verified R8)
// ---------------------------------------------------------------------------
__global__ __launch_bounds__(256)
void musum(const float* __restrict__ Kb, float* __restrict__ mu)
{
    const int bh = blockIdx.x;
    const int tid = threadIdx.x;
    const float* p = Kb + (size_t)bh * (N_ * HD_);
    float s = 0.0f;
    for (int i = tid; i < N_ * HD_; i += 256) s += fabsf(p[i]);
    for (int off = 32; off; off >>= 1) s += __shfl_down(s, off, 64);
    __shared__ float red[4];
    if ((tid & 63) == 0) red[tid >> 6] = s;
    __syncthreads();
    if (tid == 0)
        mu[bh] = (float)(N_ * C_ / 4.0) / (red[0] + red[1] + red[2] + red[3]);
}

// ---------------------------------------------------------------------------
// K3: t = k - l + y/mu; s = soft_threshold(t, 4*mu); k2 = k - s - y/mu
// (verified R8)
// ---------------------------------------------------------------------------
__global__ __launch_bounds__(256)
void ew_sk2(const float* __restrict__ Kb, const float* __restrict__ Lb,
            const float* __restrict__ Yb, const float* __restrict__ mu,
            float* __restrict__ K2b)
{
    const int i = blockIdx.x * 256 + threadIdx.x;
    const int bh = i >> 16;
    const float m = mu[bh];
    const float lm = 4.0f * m;
    const float yom = Yb[i] / m;
    const float kv = Kb[i];
    const float t = kv - Lb[i] + yom;
    const float s = (t >= lm) ? (t - lm) : ((t <= -lm) ? (t + lm) : 0.0f);
    K2b[i] = kv - s - yom;
}

// ---------------------------------------------------------------------------
// K5: y_new = 2*y + mu*(k2 - l)  (verified R8)
// ---------------------------------------------------------------------------
__global__ __launch_bounds__(256)
void ew_y(float* __restrict__ Yb, const float* __restrict__ K2b,
          const float* __restrict__ Lb, const float* __restrict__ mu)
{
    const int i = blockIdx.x * 256 + threadIdx.x;
    const int bh = i >> 16;
    const float m = mu[bh];
    Yb[i] = 2.0f * Yb[i] + m * (K2b[i] - Lb[i]);
}

// ---------------------------------------------------------------------------
// K4 flash (verified R9) + LDS cut: Ps aliased onto Ks (dead after S),
// 52.8 KB/block -> 3 blocks/CU. One extra barrier per K-tile.
// grid (16, 96) x 256.
// ---------------------------------------------------------------------------
__global__ __launch_bounds__(256)
void flash(const float* __restrict__ K2v, const float* __restrict__ Vv,
           float* __restrict__ Lout, float* __restrict__ Mrow,
           float* __restrict__ Zrow)
{
    __shared__ float Qs[64][68];
    __shared__ float Ks[64][68];          // doubles as Ps after S-compute
    __shared__ float Vs[64][68];
    __shared__ float m_sm[64], z_sm[64];

    const int tid = threadIdx.x;
    const int tx = tid & 15, ty = tid >> 4;
    const int bh = blockIdx.y;
    const int q0 = blockIdx.x * 64;
    const float* k2b = K2v + (size_t)bh * N_ * HD_;
    const float* vb  = Vv  + (size_t)bh * N_ * HD_;

    {
        int e = tid;
#pragma unroll
        for (int t = 0; t < 4; ++t, e += 256) {
            int r = e >> 4, c4 = (e & 15) << 2;
            *(float4*)&Qs[r][c4] =
                *(const float4*)(k2b + (size_t)(q0 + r) * HD_ + c4);
        }
    }
    if (tid < 64) { m_sm[tid] = -1e30f; z_sm[tid] = 0.0f; }

    float O[4][4];
#pragma unroll
    for (int i = 0; i < 4; ++i)
#pragma unroll
        for (int j = 0; j < 4; ++j) O[i][j] = 0.0f;

    for (int kt = 0; kt < 16; ++kt) {
        __syncthreads();   // prev PV reads (Ks-as-Ps, Vs) done; Q init visible
        {
            int e = tid;
#pragma unroll
            for (int t = 0; t < 4; ++t, e += 256) {
                int r = e >> 4, c4 = (e & 15) << 2;
                size_t g = (size_t)(kt * 64 + r) * HD_ + c4;
                *(float4*)&Ks[r][c4] = *(const float4*)(k2b + g);
                *(float4*)&Vs[r][c4] = *(const float4*)(vb + g);
            }
        }
        __syncthreads();

        // S[i][j] = (Q row 4ty+i) . (K row tx+16j)
        float S[4][4] = {};
#pragma unroll 4
        for (int d4 = 0; d4 < 16; ++d4) {
            float4 a[4], b[4];
#pragma unroll
            for (int i = 0; i < 4; ++i) a[i] = *(const float4*)&Qs[4 * ty + i][4 * d4];
#pragma unroll
            for (int j = 0; j < 4; ++j) b[j] = *(const float4*)&Ks[tx + 16 * j][4 * d4];
#pragma unroll
            for (int i = 0; i < 4; ++i)
#pragma unroll
                for (int j = 0; j < 4; ++j)
                    S[i][j] += a[i].x * b[j].x + a[i].y * b[j].y +
                               a[i].z * b[j].z + a[i].w * b[j].w;
        }
#pragma unroll
        for (int i = 0; i < 4; ++i)
#pragma unroll
            for (int j = 0; j < 4; ++j) S[i][j] *= SCALE_;

        float mt[4];
#pragma unroll
        for (int i = 0; i < 4; ++i)
            mt[i] = fmaxf(fmaxf(S[i][0], S[i][1]), fmaxf(S[i][2], S[i][3]));
        for (int off = 8; off; off >>= 1)
#pragma unroll
            for (int i = 0; i < 4; ++i)
                mt[i] = fmaxf(mt[i], __shfl_xor(mt[i], off, 16));

        float mnew[4], alpha[4], zs[4];
#pragma unroll
        for (int i = 0; i < 4; ++i) {
            const int r = 4 * ty + i;
            const float mo = m_sm[r];
            mnew[i] = fmaxf(mo, mt[i]);
            alpha[i] = __expf(mo - mnew[i]);
            zs[i] = 0.0f;
#pragma unroll
            for (int j = 0; j < 4; ++j) {
                S[i][j] = __expf(S[i][j] - mnew[i]);
                zs[i] += S[i][j];
            }
        }
        for (int off = 8; off; off >>= 1)
#pragma unroll
            for (int i = 0; i < 4; ++i) zs[i] += __shfl_xor(zs[i], off, 16);

        __syncthreads();   // all Ks reads complete before Ps overwrites it

#pragma unroll
        for (int i = 0; i < 4; ++i)
#pragma unroll
            for (int j = 0; j < 4; ++j)
                Ks[4 * ty + i][tx + 16 * j] = S[i][j];   // Ps := Ks storage

        if (tx == 0) {
#pragma unroll
            for (int i = 0; i < 4; ++i) {
                const int r = 4 * ty + i;
                z_sm[r] = z_sm[r] * alpha[i] + zs[i];
                m_sm[r] = mnew[i];
            }
        }
#pragma unroll
        for (int i = 0; i < 4; ++i)
#pragma unroll
            for (int j = 0; j < 4; ++j) O[i][j] *= alpha[i];

        __syncthreads();   // Ps fully written

        // O[i][c] += sum_m Ps[4ty+i][m] * Vs[m][4tx+c]
#pragma unroll 4
        for (int j4 = 0; j4 < 16; ++j4) {
            float4 vr[4];
#pragma unroll
            for (int q = 0; q < 4; ++q)
                vr[q] = *(const float4*)&Vs[4 * j4 + q][4 * tx];
#pragma unroll
            for (int i = 0; i < 4; ++i) {
                float4 pr = *(const float4*)&Ks[4 * ty + i][4 * j4];
                O[i][0] += pr.x * vr[0].x + pr.y * vr[1].x + pr.z * vr[2].x + pr.w * vr[3].x;
                O[i][1] += pr.x * vr[0].y + pr.y * vr[1].y + pr.z * vr[2].y + pr.w * vr[3].y;
                O[i][2] += pr.x * vr[0].z + pr.y * vr[1].z + pr.z * vr[2].z + pr.w * vr[3].z;
                O[i][3] += pr.x * vr[0].w + pr.y * vr[1].w + pr.z * vr[2].w + pr.w * vr[3].w;
            }
        }
    }

#pragma unroll
    for (int i = 0; i < 4; ++i) {
        const int r = 4 * ty + i;
        const float zinv = 1.0f / z_sm[r];
        float4 o4 = make_float4(O[i][0] * zinv, O[i][1] * zinv,
                                O[i][2] * zinv, O[i][3] * zinv);
        *(float4*)(Lout + ((size_t)bh * N_ + q0 + r) * HD_ + 4 * tx) = o4;
    }
    if (tx == 0) {
#pragma unroll
        for (int i = 0; i < 4; ++i) {
            const int r = 4 * ty + i;
            Mrow[(size_t)bh * N_ + q0 + r] = m_sm[r];
            Zrow[(size_t)bh * N_ + q0 + r] = z_sm[r];
        }
    }
}

// ---------------------------------------------------------------------------
// K6: recompute final scores from k2 + saved (m, Z); write fp32 attn.
// (verified R9)  grid (16, 96) x 256.
// ---------------------------------------------------------------------------
__global__ __launch_bounds__(256)
void attn_out(const float* __restrict__ K2v, const float* __restrict__ Mrow,
              const float* __restrict__ Zrow, float* __restrict__ A)
{
    __shared__ float Qs[64][68];
    __shared__ float Ks[64][68];
    const int tid = threadIdx.x;
    const int tx = tid & 15, ty = tid >> 4;
    const int bh = blockIdx.y;
    const int q0 = blockIdx.x * 64;
    const float* k2b = K2v + (size_t)bh * N_ * HD_;

    {
        int e = tid;
#pragma unroll
        for (int t = 0; t < 4; ++t, e += 256) {
            int r = e >> 4, c4 = (e & 15) << 2;
            *(float4*)&Qs[r][c4] =
                *(const float4*)(k2b + (size_t)(q0 + r) * HD_ + c4);
        }
    }
    float mi[4], zi[4];
#pragma unroll
    for (int i = 0; i < 4; ++i) {
        const int r = q0 + 4 * ty + i;
        mi[i] = Mrow[(size_t)bh * N_ + r];
        zi[i] = 1.0f / Zrow[(size_t)bh * N_ + r];
    }

    for (int kt = 0; kt < 16; ++kt) {
        __syncthreads();
        {
            int e = tid;
#pragma unroll
            for (int t = 0; t < 4; ++t, e += 256) {
                int r = e >> 4, c4 = (e & 15) << 2;
                *(float4*)&Ks[r][c4] =
                    *(const float4*)(k2b + (size_t)(kt * 64 + r) * HD_ + c4);
            }
        }
        __syncthreads();

        float S[4][4] = {};
#pragma unroll 4
        for (int d4 = 0; d4 < 16; ++d4) {
            float4 a[4], b[4];
#pragma unroll
            for (int i = 0; i < 4; ++i) a[i] = *(const float4*)&Qs[4 * ty + i][4 * d4];
#pragma unroll
            for (int j = 0; j < 4; ++j) b[j] = *(const float4*)&Ks[tx + 16 * j][4 * d4];
#pragma unroll
            for (int i = 0; i < 4; ++i)
#pragma unroll
                for (int j = 0; j < 4; ++j)
                    S[i][j] += a[i].x * b[j].x + a[i].y * b[j].y +
                               a[i].z * b[j].z + a[i].w * b[j].w;
        }
#pragma unroll
        for (int i = 0; i < 4; ++i) {
            float* arow = A + ((size_t)(bh * N_ + q0 + 4 * ty + i)) * N_ + kt * 64;
#pragma unroll
            for (int j = 0; j < 4; ++j)
                arow[tx + 16 * j] = __expf(S[i][j] * SCALE_ - mi[i]) * zi[i];
        }
    }
}

// ---------------------------------------------------------------------------
// K7 tiled proj: out = l_t @ W_proj + b_proj (fp32).
// grid (768/64=12, 8192/64=128), block 256.
// ---------------------------------------------------------------------------
__global__ __launch_bounds__(256)
void proj_gemm(const float* __restrict__ Lb, const float* __restrict__ W,
               const float* __restrict__ bias, float* __restrict__ Out)
{
    __shared__ float As[64][17];
    __shared__ float Bs[16][68];
    const int tid = threadIdx.x;
    const int tx = tid & 15, ty = tid >> 4;
    const int m0 = blockIdx.y * 64;
    const int c0 = blockIdx.x * 64;
    const int ar = tid >> 2, ak4 = (tid & 3) << 2;
    const int bk = tid >> 4, bc4 = (tid & 15) << 2;

    const int am = m0 + ar;
    const int ab = am >> 10, an = am & 1023;

    float acc[4][4] = {};

    for (int kt = 0; kt < 48; ++kt) {
        __syncthreads();
        {
            const int kk0 = kt * 16 + ak4;
            const int h = kk0 >> 6, d = kk0 & 63;
            float4 av = *(const float4*)(Lb + ((size_t)(ab * H_ + h) * N_ + an) * HD_ + d);
            As[ar][ak4 + 0] = av.x; As[ar][ak4 + 1] = av.y;
            As[ar][ak4 + 2] = av.z; As[ar][ak4 + 3] = av.w;
        }
        *(float4*)&Bs[bk][bc4] =
            *(const float4*)(W + (size_t)(kt * 16 + bk) * C_ + c0 + bc4);
        __syncthreads();
#pragma unroll
        for (int kk = 0; kk < 16; ++kk) {
            float a_[4];
#pragma unroll
            for (int i = 0; i < 4; ++i) a_[i] = As[4 * ty + i][kk];
            float4 b_ = *(const float4*)&Bs[kk][4 * tx];
#pragma unroll
            for (int i = 0; i < 4; ++i) {
                acc[i][0] += a_[i] * b_.x;
                acc[i][1] += a_[i] * b_.y;
                acc[i][2] += a_[i] * b_.z;
                acc[i][3] += a_[i] * b_.w;
            }
        }
    }

    const int cb = c0 + 4 * tx;
    const float b0 = bias[cb + 0], b1 = bias[cb + 1];
    const float b2 = bias[cb + 2], b3 = bias[cb + 3];
#pragma unroll
    for (int i = 0; i < 4; ++i) {
        const int m = m0 + 4 * ty + i;
        float4 o;
        o.x = acc[i][0] + b0;
        o.y = acc[i][1] + b1;
        o.z = acc[i][2] + b2;
        o.w = acc[i][3] + b3;
        *(float4*)(Out + (size_t)m * C_ + cb) = o;
    }
}

// ---------------------------------------------------------------------------
// d_out is FLOAT32: out = d_out[0 .. 6291456), attn = d_out[6291456 .. ).
// ws (floats): kb@0, vb@SZ, lb@2SZ, yb@3SZ, k2b@4SZ, mu@5SZ(128), rowm, rowz.
// ---------------------------------------------------------------------------
extern "C" void kernel_launch(void* const* d_in, const int* in_sizes, int n_in,
                              void* d_out, int out_size, void* d_ws, size_t ws_size,
                              hipStream_t stream)
{
    (void)in_sizes; (void)n_in; (void)out_size; (void)ws_size;

    const float* x  = (const float*)d_in[0];
    const float* Wq = (const float*)d_in[1];
    const float* bq = (const float*)d_in[2];
    const float* Wp = (const float*)d_in[3];
    const float* bp = (const float*)d_in[4];

    float* out_f  = (float*)d_out;
    float* attn_f = out_f + (size_t)B_ * N_ * C_;

    const size_t SZ = (size_t)BH_ * N_ * HD_;   // 6,291,456 floats
    float* ws   = (float*)d_ws;
    float* kb   = ws;
    float* vb   = ws + SZ;
    float* lb   = ws + 2 * SZ;
    float* yb   = ws + 3 * SZ;
    float* k2b  = ws + 4 * SZ;
    float* mu   = ws + 5 * SZ;                  // 96 floats (pad 128)
    float* rowm = mu + 128;                     // BH*N
    float* rowz = rowm + (size_t)BH_ * N_;      // BH*N

    hipMemsetAsync(lb, 0, SZ * sizeof(float), stream);
    hipMemsetAsync(yb, 0, SZ * sizeof(float), stream);

    qkv_gemm<<<dim3(24, 128), 256, 0, stream>>>(x, Wq, bq, kb, vb);
    musum<<<96, 256, 0, stream>>>(kb, mu);

    for (int it = 0; it <= NIT_; ++it) {
        ew_sk2<<<24576, 256, 0, stream>>>(kb, lb, yb, mu, k2b);
        flash<<<dim3(16, 96), 256, 0, stream>>>(k2b, vb, lb, rowm, rowz);
        if (it < NIT_)
            ew_y<<<24576, 256, 0, stream>>>(yb, k2b, lb, mu);
    }

    attn_out<<<dim3(16, 96), 256, 0, stream>>>(k2b, rowm, rowz, attn_f);
    proj_gemm<<<dim3(12, 128), 256, 0, stream>>>(lb, Wp, bp, out_f);
}